// Round 21
// baseline (371.533 us; speedup 1.0000x reference)
//
#include <hip/hip_runtime.h>
#include <hip/hip_bf16.h>
#include <math.h>

#define NPTS 2048
#define NCLOUD 32
#define NTOT (NPTS*NCLOUD)
#define CIN 64
#define COUT 128
#define KNN 16
#define NCAND 32           // 2 col-halves x exact-merged top-16
#define PREF_MARGIN 0.6f   // prefilter margin (approx-key err ~0.3 + key quant)

typedef __attribute__((ext_vector_type(8))) short short8v;   // 8 bf16 (4 VGPR)
typedef __attribute__((ext_vector_type(4))) float float4v;   // 4 fp32

__device__ __forceinline__ unsigned short f2bf(float f) {    // RNE float->bf16
    unsigned u = __float_as_uint(f);
    return (unsigned short)((u + 0x7fffu + ((u >> 16) & 1u)) >> 16);
}
__device__ __forceinline__ unsigned fenc(float f) {          // monotone float->uint
    unsigned u = __float_as_uint(f);
    return u ^ (unsigned)(((int)u >> 31) | 0x80000000);
}
__device__ __forceinline__ float fdec(unsigned u) {          // inverse of fenc
    unsigned m = (unsigned)(((int)(~u) >> 31)) | 0x80000000u;
    return __uint_as_float(u ^ m);
}

// np.sum pairwise-8 replication for 64 squares (fp32, no FMA) — BIT-IDENTICAL recipe.
__device__ __forceinline__ float np_sq64(const float* __restrict__ v)
{
    float r[8];
    #pragma unroll
    for (int j = 0; j < 8; ++j) r[j] = __fmul_rn(v[j], v[j]);
    #pragma unroll
    for (int i = 1; i < 8; ++i)
        #pragma unroll
        for (int j = 0; j < 8; ++j) r[j] = __fadd_rn(r[j], __fmul_rn(v[8*i+j], v[8*i+j]));
    return __fadd_rn(__fadd_rn(__fadd_rn(r[0],r[1]), __fadd_rn(r[2],r[3])),
                     __fadd_rn(__fadd_rn(r[4],r[5]), __fadd_rn(r[6],r[7])));
}

// ---------------- K0: bf16 row plane + MFMA-fragment-tiled plane + |q|^2 + deg zero ----------------
__global__ void k0_prep(const float* __restrict__ x, unsigned short* __restrict__ xhi,
                        unsigned short* __restrict__ xat,
                        float* __restrict__ sq, float* __restrict__ sqb, int* __restrict__ deg)
{
    const int p = blockIdx.x * 256 + threadIdx.x;
    const int tile = p >> 4, j = p & 15;
    const float* src = x + (size_t)p * CIN;
    float e[CIN];
    #pragma unroll
    for (int i = 0; i < 8; ++i) {                  // i: 8-dim group; quad=i&3, h=i>>2
        float4 v0 = *reinterpret_cast<const float4*>(src + 8*i);
        float4 v1 = *reinterpret_cast<const float4*>(src + 8*i + 4);
        e[8*i+0]=v0.x; e[8*i+1]=v0.y; e[8*i+2]=v0.z; e[8*i+3]=v0.w;
        e[8*i+4]=v1.x; e[8*i+5]=v1.y; e[8*i+6]=v1.z; e[8*i+7]=v1.w;
        short8v h;
        #pragma unroll
        for (int u = 0; u < 8; ++u) h[u] = (short)f2bf(e[8*i+u]);
        *reinterpret_cast<short8v*>(xhi + (size_t)p*CIN + 8*i) = h;
        *reinterpret_cast<short8v*>(xat + (size_t)tile*1024 + (i>>2)*512 + ((i&3)*16 + j)*8) = h;
    }
    const float s = np_sq64(e);
    sq[p]  = s;           // exact (k2)
    sqb[p] = s + 16.f;    // biased (k1 keys; always > 0)
    deg[p] = 0;           // replaces memset
}

// Comparators: KA = ascending on key[], DD = descending on kd[].
#define KA(a,b) { const unsigned _x = key[a], _y = key[b]; key[a] = min(_x,_y); key[b] = max(_x,_y); }
#define DD(a,b) { const unsigned _x = kd[a],  _y = kd[b];  kd[a]  = max(_x,_y); kd[b]  = min(_x,_y); }
#define DDMERGE \
    DD(0,8)  DD(1,9)  DD(2,10) DD(3,11) DD(4,12) DD(5,13) DD(6,14) DD(7,15) \
    DD(0,4)  DD(1,5)  DD(2,6)  DD(3,7)  DD(8,12) DD(9,13) DD(10,14) DD(11,15) \
    DD(0,2)  DD(1,3)  DD(4,6)  DD(5,7)  DD(8,10) DD(9,11) DD(12,14) DD(13,15) \
    DD(0,1)  DD(2,3)  DD(4,5)  DD(6,7)  DD(8,9)  DD(10,11) DD(12,13) DD(14,15)

// ---------------- K1: MFMA swapped-operand KNN + Batcher-63 top-16 + cross-quad merge ----------------
__global__ __launch_bounds__(256,1) void k1_knn(const unsigned short* __restrict__ xhi,
                                                const unsigned short* __restrict__ xat,
                                                const float* __restrict__ sqb,
                                                unsigned* __restrict__ cand)
{
    const int wid  = ((blockIdx.x & 7) << 8) + (blockIdx.x >> 3);  // XCD swizzle (4 clouds/XCD)
    const int o    = wid >> 1;           // row group (64 rows)
    const int half = wid & 1;            // column half
    const int wave = threadIdx.x >> 6;
    const int lane = threadIdx.x & 63;
    const int j    = lane & 15;
    const int quad = lane >> 4;
    const int rowglob = o*64 + wave*16 + j;
    const int cloud   = rowglob >> 11;
    const int cbase   = cloud << 11;               // cloud base point id

    const short8v bhi0 = *reinterpret_cast<const short8v*>(xhi + (size_t)rowglob*CIN + quad*8);
    const short8v bhi1 = *reinterpret_cast<const short8v*>(xhi + (size_t)rowglob*CIN + quad*8 + 32);

    unsigned kd[16];                   // DESC: kd[0] = worst kept
    #pragma unroll
    for (int k = 0; k < 16; ++k) kd[k] = 0xFFFFFFFFu;

    const unsigned short* pt0 = xat + (size_t)(cloud*128 + half*64)*1024 + lane*8;
    const float*          ps0 = sqb + cbase + half*1024 + quad*4;

    short8v pfa0 = *reinterpret_cast<const short8v*>(pt0);
    short8v pfa1 = *reinterpret_cast<const short8v*>(pt0 + 512);

    for (int it4 = 0; it4 < 16; ++it4) {           // 16 batches x 4 tiles x 16 cols
        unsigned key[16];
        const unsigned idb = (unsigned)(half*1024 + it4*64 + quad*4) | 0x80000000u;

        {
            float4v acc0 = {0.f,0.f,0.f,0.f}, acc1 = {0.f,0.f,0.f,0.f};
            acc0 = __builtin_amdgcn_mfma_f32_16x16x32_bf16(pfa0, bhi0, acc0, 0,0,0);
            acc1 = __builtin_amdgcn_mfma_f32_16x16x32_bf16(pfa1, bhi1, acc1, 0,0,0);
            const float4v sqv = *reinterpret_cast<const float4v*>(ps0 + it4*64);
            #pragma unroll
            for (int r = 0; r < 4; ++r) {
                const float s = fmaf(-2.f, acc0[r] + acc1[r], sqv[r]);
                key[r] = (__float_as_uint(s) & 0xFFFFF800u) | (idb + (unsigned)r);
            }
        }
        {
            const int nxt = (it4 < 15) ? it4 + 1 : 15;
            const unsigned short* pan = pt0 + (size_t)(nxt*4)*1024;
            pfa0 = *reinterpret_cast<const short8v*>(pan);
            pfa1 = *reinterpret_cast<const short8v*>(pan + 512);
        }
        #pragma unroll
        for (int sub = 1; sub < 4; ++sub) {
            const unsigned short* pa = pt0 + (size_t)(it4*4 + sub)*1024;
            const short8v a0 = *reinterpret_cast<const short8v*>(pa);
            const short8v a1 = *reinterpret_cast<const short8v*>(pa + 512);
            float4v acc0 = {0.f,0.f,0.f,0.f}, acc1 = {0.f,0.f,0.f,0.f};
            acc0 = __builtin_amdgcn_mfma_f32_16x16x32_bf16(a0, bhi0, acc0, 0,0,0);
            acc1 = __builtin_amdgcn_mfma_f32_16x16x32_bf16(a1, bhi1, acc1, 0,0,0);
            const float4v sqv = *reinterpret_cast<const float4v*>(ps0 + it4*64 + sub*16);
            #pragma unroll
            for (int r = 0; r < 4; ++r) {
                const float s = fmaf(-2.f, acc0[r] + acc1[r], sqv[r]);
                key[sub*4 + r] = (__float_as_uint(s) & 0xFFFFF800u) | (idb + (unsigned)(sub*16 + r));
            }
        }

        // Batcher odd-even mergesort-16 ascending (63 comparators)
        KA(0,1) KA(2,3) KA(4,5) KA(6,7)
        KA(0,2) KA(1,3) KA(4,6) KA(5,7)
        KA(1,2) KA(5,6)
        KA(0,4) KA(1,5) KA(2,6) KA(3,7)
        KA(2,4) KA(3,5)
        KA(1,2) KA(3,4) KA(5,6)
        KA(8,9) KA(10,11) KA(12,13) KA(14,15)
        KA(8,10) KA(9,11) KA(12,14) KA(13,15)
        KA(9,10) KA(13,14)
        KA(8,12) KA(9,13) KA(10,14) KA(11,15)
        KA(10,12) KA(11,13)
        KA(9,10) KA(11,12) KA(13,14)
        KA(0,8) KA(1,9) KA(2,10) KA(3,11) KA(4,12) KA(5,13) KA(6,14) KA(7,15)
        KA(4,8) KA(5,9) KA(6,10) KA(7,11)
        KA(2,4) KA(3,5) KA(6,8) KA(7,9) KA(10,12) KA(11,13)
        KA(1,2) KA(3,4) KA(5,6) KA(7,8) KA(9,10) KA(11,12) KA(13,14)

        #pragma unroll
        for (int i = 0; i < 16; ++i) kd[i] = min(kd[i], key[i]);

        DDMERGE
    }

    // ---- cross-quad merge: 4 sorted-desc lists -> half's exact approx-top-16 ----
    #pragma unroll
    for (int lvl = 16; lvl <= 32; lvl <<= 1) {
        unsigned key[16];
        #pragma unroll
        for (int i = 0; i < 16; ++i) key[i] = __shfl_xor(kd[15-i], lvl);  // partner, reversed (asc)
        #pragma unroll
        for (int i = 0; i < 16; ++i) kd[i] = min(kd[i], key[i]);          // bottom-16 of union
        DDMERGE                                                            // restore desc
    }

    if (quad == 0) {                    // one lane per row writes the merged 16 keys
        unsigned* dst = cand + (size_t)rowglob*NCAND + half*16;
        #pragma unroll
        for (int k = 0; k < 4; ++k) {
            int4 w4 = { (int)kd[4*k+0], (int)kd[4*k+1], (int)kd[4*k+2], (int)kd[4*k+3] };
            *reinterpret_cast<int4*>(dst + 4*k) = w4;
        }
    }
}

// ---------------- K2: 2 points/wave; cross-lane bitonic sort-32 replaces radix+compaction ----------------
// 32 unique keys (id in low bits) one-per-lane: 15-stage shfl_xor bitonic sort (j<=16
// stays within 32-lane halves). 16th key's bit-11 floor == the old radix T exactly ->
// identical Tk -> identical survivor sets -> identical output. Survivors = lane prefix
// (sorted), so LDS compaction + __syncthreads are GONE (half-waves fully decoupled).
__global__ void k2_refine(const float* __restrict__ x, const float* __restrict__ sq,
                          const unsigned* __restrict__ cand,
                          int* __restrict__ nbr, int* __restrict__ deg)
{
    const int hw   = threadIdx.x >> 5;                      // half-wave id 0..7
    const int w    = blockIdx.x * 8 + hw;                   // point id
    const int lane = threadIdx.x & 31;                      // lane within half
    const int gl   = threadIdx.x & 63;                      // lane within wave
    const unsigned long long hmask = (gl >= 32) ? 0xFFFFFFFF00000000ull : 0x00000000FFFFFFFFull;
    const int b    = w >> 11;
    const int ploc = w & (NPTS-1);
    const int cbase = b * NPTS;
    const float* xc = x + (size_t)cbase * CIN;
    const float* xp = xc + (size_t)ploc * CIN;

    // --- issue HBM loads up front (overlap with sort) ---
    unsigned kv = cand[(size_t)w * NCAND + lane];
    float xpl[CIN];
    #pragma unroll
    for (int i = 0; i < CIN/4; ++i) {
        float4 v = *reinterpret_cast<const float4*>(xp + 4*i);
        xpl[4*i+0]=v.x; xpl[4*i+1]=v.y; xpl[4*i+2]=v.z; xpl[4*i+3]=v.w;
    }
    const float sqp = sq[w];

    if ((int)(kv & 0x7FFu) == ploc) kv = 0xFFFFFFFFu;       // self-mask (sorts to top)

    // --- bitonic sort-32 across lanes (ascending by lane index within each half) ---
    #pragma unroll
    for (int k = 2; k <= 32; k <<= 1) {
        #pragma unroll
        for (int jj = k >> 1; jj >= 1; jj >>= 1) {
            const unsigned pv = __shfl_xor(kv, jj);         // jj<=16: stays within 32-half
            const bool takeMin = ((lane & k) == 0) == ((lane & jj) == 0);
            kv = takeMin ? min(kv, pv) : max(kv, pv);
        }
    }

    // --- window: 16th key's bit-11 floor == old radix T (bit-identical Tk) ---
    const unsigned k16key = __shfl(kv, 15, 32);
    const float d16 = fdec(k16key & 0xFFFFF800u);
    const unsigned Tk = (fenc(d16 + PREF_MARGIN) & 0xFFFFF800u) | 0x7FFu;  // inclusive

    const bool sv = (kv <= Tk);
    const int n = __popcll(__ballot(sv) & hmask);           // survivors = lanes 0..n-1 (prefix)
    const int qloc = (int)(kv & 0x7FFu);

    // --- fast path (per half): survivors == top-16 set ---
    if (n == KNN) {
        if (lane < KNN) {
            const int ng = cbase + qloc;
            nbr[(size_t)w * KNN + lane] = ng;
            atomicAdd(&deg[ng], 1);
        }
        return;
    }

    // --- exact np-faithful distance for survivors (1 chain/lane, lanes < n) ---
    float dot = 0.f;                               // sequential fp32, no FMA (verified recipe)
    if (lane < n) {
        const float* xq = xc + (size_t)qloc * CIN;
        #pragma unroll
        for (int i = 0; i < 8; ++i) {
            float4 v0 = *reinterpret_cast<const float4*>(xq + 8*i);
            float4 v1 = *reinterpret_cast<const float4*>(xq + 8*i + 4);
            float g[8] = {v0.x,v0.y,v0.z,v0.w,v1.x,v1.y,v1.z,v1.w};
            #pragma unroll
            for (int u = 0; u < 8; ++u)
                dot = __fadd_rn(dot, __fmul_rn(xpl[8*i+u], g[u]));
        }
    }
    const float sqq = sq[cbase + ((lane < n) ? qloc : 0)];
    float d = __fsub_rn(__fadd_rn(sqp, sqq), __fmul_rn(2.f, dot));
    int qcmp = qloc;
    if (lane >= n) { d = INFINITY; qcmp = 0x7fffffff; }

    // --- exact (d, idx) total-order rank, width-32 shuffles, 4-wide ---
    const int nn = (n + 3) & ~3;
    int rank = 0;
    for (int s = 0; s < nn; s += 4) {
        const float d0 = __shfl(d, s, 32),   d1 = __shfl(d, s+1, 32);
        const float d2 = __shfl(d, s+2, 32), d3 = __shfl(d, s+3, 32);
        const int   q0 = __shfl(qcmp, s, 32),   q1 = __shfl(qcmp, s+1, 32);
        const int   q2 = __shfl(qcmp, s+2, 32), q3 = __shfl(qcmp, s+3, 32);
        rank += (d0 < d || (d0 == d && q0 < qcmp)) ? 1 : 0;
        rank += (d1 < d || (d1 == d && q1 < qcmp)) ? 1 : 0;
        rank += (d2 < d || (d2 == d && q2 < qcmp)) ? 1 : 0;
        rank += (d3 < d || (d3 == d && q3 < qcmp)) ? 1 : 0;
    }
    if (lane < n && rank < KNN) {
        const int ng = cbase + qloc;
        nbr[(size_t)w * KNN + rank] = ng;
        atomicAdd(&deg[ng], 1);
    }
}

// ---------------- K3s: prefix scan (+ zeroes sums, replacing memset) ----------------
__global__ void k3_scan(int* __restrict__ deg, int* __restrict__ rowstart, double* __restrict__ sums)
{
    __shared__ int part[256];
    __shared__ int base[257];
    const int t = threadIdx.x;
    sums[t] = 0.0;
    int s = 0;
    for (int i = 0; i < 256; ++i) s += deg[t*256 + i];
    part[t] = s;
    __syncthreads();
    if (t == 0) {
        int acc = 0;
        for (int i = 0; i < 256; ++i) { base[i] = acc; acc += part[i]; }
        base[256] = acc;
    }
    __syncthreads();
    int run = base[t];
    for (int i = 0; i < 256; ++i) {
        const int dv = deg[t*256 + i];
        rowstart[t*256 + i] = run;
        deg[t*256 + i] = run;          // deg becomes the write cursor for k3_place
        run += dv;
    }
    if (t == 0) rowstart[NTOT] = base[256];
}

// ---------------- K3a: place edges into reverse lists (counter atomics only) ----------------
__global__ void k3_place(const int* __restrict__ nbr, int* __restrict__ wcur, int* __restrict__ rev)
{
    const int e = blockIdx.x * 256 + threadIdx.x;
    const int c = e >> 4;
    const int n = nbr[e];
    const int pos = atomicAdd(&wcur[n], 1);
    rev[pos] = c;
}

// ---------------- K3g: gather-max, direct broadcast index loads, 8 rows in flight ----------------
__global__ void k3_gather(const float* __restrict__ x, const int* __restrict__ rowstart,
                          const int* __restrict__ rev, float* __restrict__ pooled)
{
    const int n    = blockIdx.x * 4 + (threadIdx.x >> 6);
    const int lane = threadIdx.x & 63;
    const int s = rowstart[n];
    const int e = rowstart[n+1];
    float a0 = -INFINITY, a1 = -INFINITY, a2 = -INFINITY, a3 = -INFINITY;
    int i = s;
    for (; i + 8 <= e; i += 8) {
        const int c0 = rev[i+0], c1 = rev[i+1], c2 = rev[i+2], c3 = rev[i+3];
        const int c4 = rev[i+4], c5 = rev[i+5], c6 = rev[i+6], c7 = rev[i+7];
        const float v0 = x[(size_t)c0 * CIN + lane];
        const float v1 = x[(size_t)c1 * CIN + lane];
        const float v2 = x[(size_t)c2 * CIN + lane];
        const float v3 = x[(size_t)c3 * CIN + lane];
        const float v4 = x[(size_t)c4 * CIN + lane];
        const float v5 = x[(size_t)c5 * CIN + lane];
        const float v6 = x[(size_t)c6 * CIN + lane];
        const float v7 = x[(size_t)c7 * CIN + lane];
        a0 = fmaxf(a0, v0); a1 = fmaxf(a1, v1); a2 = fmaxf(a2, v2); a3 = fmaxf(a3, v3);
        a0 = fmaxf(a0, v4); a1 = fmaxf(a1, v5); a2 = fmaxf(a2, v6); a3 = fmaxf(a3, v7);
    }
    for (; i < e; ++i)
        a0 = fmaxf(a0, x[(size_t)rev[i] * CIN + lane]);
    float acc = fmaxf(fmaxf(a0, a1), fmaxf(a2, a3));
    if (e == s) acc = 0.f;                                  // empty row -> 0 (torch_scatter)
    pooled[(size_t)n * CIN + lane] = acc;
}

// ---------------- K4: y = pooled @ W^T + b, with fused per-channel stats ----------------
__global__ __launch_bounds__(256,2) void k4_linear(const float* __restrict__ pooled, const float* __restrict__ W,
                                                   const float* __restrict__ bias, float* __restrict__ y,
                                                   double* __restrict__ sums)
{
    __shared__ float wl[COUT*68];
    __shared__ float pl[64*68];     // reused post-loop as 2x[16][128] stat partials
    const int t  = threadIdx.x;
    const int r0 = blockIdx.x * 64;
    for (int i = 0; i < (COUT*CIN)/256; ++i) {
        int linear = t + 256*i;
        int c = linear >> 6, k = linear & 63;
        wl[c*68 + k] = W[linear];
    }
    for (int i = 0; i < (64*CIN)/256; ++i) {
        int linear = t + 256*i;
        int r = linear >> 6, k = linear & 63;
        pl[r*68 + k] = pooled[(size_t)(r0 + r)*CIN + k];
    }
    __syncthreads();
    const int tx = t & 15;
    const int ty = t >> 4;
    float acc[4][8];
    #pragma unroll
    for (int j = 0; j < 8; ++j) {
        float bj = bias[tx + 16*j];
        #pragma unroll
        for (int i = 0; i < 4; ++i) acc[i][j] = bj;
    }
    for (int k = 0; k < CIN; k += 4) {
        float4 a[4], bb[8];
        #pragma unroll
        for (int i = 0; i < 4; ++i) a[i]  = *reinterpret_cast<const float4*>(&pl[(ty*4+i)*68 + k]);
        #pragma unroll
        for (int j = 0; j < 8; ++j) bb[j] = *reinterpret_cast<const float4*>(&wl[(tx+16*j)*68 + k]);
        #pragma unroll
        for (int i = 0; i < 4; ++i)
            #pragma unroll
            for (int j = 0; j < 8; ++j) {
                acc[i][j] = fmaf(a[i].x, bb[j].x, acc[i][j]);
                acc[i][j] = fmaf(a[i].y, bb[j].y, acc[i][j]);
                acc[i][j] = fmaf(a[i].z, bb[j].z, acc[i][j]);
                acc[i][j] = fmaf(a[i].w, bb[j].w, acc[i][j]);
            }
    }
    #pragma unroll
    for (int i = 0; i < 4; ++i) {
        float* dst = y + (size_t)(r0 + ty*4 + i) * COUT;
        #pragma unroll
        for (int j = 0; j < 8; ++j) dst[tx + 16*j] = acc[i][j];
    }
    // --- fused stats ---
    __syncthreads();
    #pragma unroll
    for (int j = 0; j < 8; ++j) {
        float s  = ((acc[0][j] + acc[1][j]) + (acc[2][j] + acc[3][j]));
        float ss = ((acc[0][j]*acc[0][j] + acc[1][j]*acc[1][j]) +
                    (acc[2][j]*acc[2][j] + acc[3][j]*acc[3][j]));
        pl[ty*COUT + tx + 16*j]        = s;
        pl[2048 + ty*COUT + tx + 16*j] = ss;
    }
    __syncthreads();
    if (t < COUT) {
        double S = 0.0, SS = 0.0;
        #pragma unroll
        for (int r = 0; r < 16; ++r) {
            S  += (double)pl[r*COUT + t];
            SS += (double)pl[2048 + r*COUT + t];
        }
        atomicAdd(&sums[t], S);
        atomicAdd(&sums[COUT + t], SS);
    }
}

// ---------------- K6: BN scale/shift ----------------
__global__ void k6_bnparam(const double* __restrict__ sums, const float* __restrict__ gamma,
                           const float* __restrict__ beta, float* __restrict__ scsh)
{
    const int t = threadIdx.x;
    const double mean = sums[t] * (1.0/NTOT);
    const double var  = sums[COUT + t] * (1.0/NTOT) - mean*mean;
    const float inv   = (float)rsqrt(var + 1e-5);
    const float sc    = inv * gamma[t];
    scsh[t]        = sc;
    scsh[COUT + t] = beta[t] - (float)mean * sc;
}

// ---------------- K7: out = relu(y*scale + shift) ----------------
__global__ void k7_bnrelu(const float* __restrict__ y, const float* __restrict__ scsh, float* __restrict__ out)
{
    const int g    = blockIdx.x * blockDim.x + threadIdx.x;
    const int base = g * 4;
    float4 v = *reinterpret_cast<const float4*>(y + base);
    const int ch = base & (COUT-1);
    float4 o;
    o.x = fmaxf(0.f, fmaf(v.x, scsh[ch+0], scsh[COUT+ch+0]));
    o.y = fmaxf(0.f, fmaf(v.y, scsh[ch+1], scsh[COUT+ch+1]));
    o.z = fmaxf(0.f, fmaf(v.z, scsh[ch+2], scsh[COUT+ch+2]));
    o.w = fmaxf(0.f, fmaf(v.w, scsh[ch+3], scsh[COUT+ch+3]));
    *reinterpret_cast<float4*>(out + base) = o;
}

extern "C" void kernel_launch(void* const* d_in, const int* in_sizes, int n_in,
                              void* d_out, int out_size, void* d_ws, size_t ws_size,
                              hipStream_t stream)
{
    const float* x     = (const float*)d_in[0];
    const float* W     = (const float*)d_in[2];
    const float* bias  = (const float*)d_in[3];
    const float* gamma = (const float*)d_in[4];
    const float* beta  = (const float*)d_in[5];
    float* out = (float*)d_out;

    // Workspace — explicit 16B-aligned byte offsets (layout identical to round 20):
    char* ws = (char*)d_ws;
    unsigned short* xhi = (unsigned short*)ws;
    unsigned short* xat = (unsigned short*)(ws + (size_t)NTOT*128);
    float*    pooled   = (float*)ws;
    unsigned* cand     = (unsigned*)(ws + (size_t)NTOT*256);
    float*    y        = (float*)(ws + (size_t)NTOT*256);
    int*      nbr      = (int*)(ws + (size_t)NTOT*768);
    int*      deg      = (int*)(ws + (size_t)NTOT*832);            // becomes wcur after k3_scan
    int*      rowstart = (int*)(ws + (size_t)NTOT*836);
    int*      rev      = (int*)(ws + (size_t)NTOT*840 + 16);
    float*    sqb      = (float*)rev;                              // aliased: k0->k1 only
    float*    sq       = (float*)(ws + (size_t)NTOT*904 + 16);
    double*   sums     = (double*)(ws + (size_t)NTOT*908 + 16);    // 16B aligned
    float*    scsh     = (float*)(ws + (size_t)NTOT*908 + 16 + 2048);

    k0_prep  <<<NTOT/256,   256, 0, stream>>>(x, xhi, xat, sq, sqb, deg);
    k1_knn   <<<NTOT/32,    256, 0, stream>>>(xhi, xat, sqb, cand);   // 2048 blocks
    k2_refine<<<NTOT/8,     256, 0, stream>>>(x, sq, cand, nbr, deg); // 2 points/wave, no LDS

    k3_scan  <<<1,          256, 0, stream>>>(deg, rowstart, sums);
    k3_place <<<NTOT*KNN/256,256,0, stream>>>(nbr, deg, rev);
    k3_gather<<<NTOT/4,     256, 0, stream>>>(x, rowstart, rev, pooled);

    k4_linear <<<NTOT/64, 256, 0, stream>>>(pooled, W, bias, y, sums);
    k6_bnparam<<<1,      COUT, 0, stream>>>(sums, gamma, beta, scsh);
    k7_bnrelu <<<(NTOT*COUT/4)/256, 256, 0, stream>>>(y, scsh, out);
}

// Round 22
// 339.173 us; speedup vs baseline: 1.0954x; 1.0954x over previous
//
#include <hip/hip_runtime.h>
#include <hip/hip_bf16.h>
#include <math.h>

#define NPTS 2048
#define NCLOUD 32
#define NTOT (NPTS*NCLOUD)
#define CIN 64
#define COUT 128
#define KNN 16
#define NCAND 32           // 2 col-halves x exact-merged top-16
#define PREF_MARGIN 0.6f   // prefilter margin (approx-key err ~0.3 + key quant)

typedef __attribute__((ext_vector_type(8))) short short8v;   // 8 bf16 (4 VGPR)
typedef __attribute__((ext_vector_type(4))) float float4v;   // 4 fp32

__device__ __forceinline__ unsigned short f2bf(float f) {    // RNE float->bf16
    unsigned u = __float_as_uint(f);
    return (unsigned short)((u + 0x7fffu + ((u >> 16) & 1u)) >> 16);
}
__device__ __forceinline__ unsigned fenc(float f) {          // monotone float->uint
    unsigned u = __float_as_uint(f);
    return u ^ (unsigned)(((int)u >> 31) | 0x80000000);
}
__device__ __forceinline__ float fdec(unsigned u) {          // inverse of fenc
    unsigned m = (unsigned)(((int)(~u) >> 31)) | 0x80000000u;
    return __uint_as_float(u ^ m);
}

// np.sum pairwise-8 replication for 64 squares (fp32, no FMA) — BIT-IDENTICAL recipe.
__device__ __forceinline__ float np_sq64(const float* __restrict__ v)
{
    float r[8];
    #pragma unroll
    for (int j = 0; j < 8; ++j) r[j] = __fmul_rn(v[j], v[j]);
    #pragma unroll
    for (int i = 1; i < 8; ++i)
        #pragma unroll
        for (int j = 0; j < 8; ++j) r[j] = __fadd_rn(r[j], __fmul_rn(v[8*i+j], v[8*i+j]));
    return __fadd_rn(__fadd_rn(__fadd_rn(r[0],r[1]), __fadd_rn(r[2],r[3])),
                     __fadd_rn(__fadd_rn(r[4],r[5]), __fadd_rn(r[6],r[7])));
}

// ---------------- K0: bf16 row plane + MFMA-fragment-tiled plane + |q|^2 + deg zero ----------------
__global__ void k0_prep(const float* __restrict__ x, unsigned short* __restrict__ xhi,
                        unsigned short* __restrict__ xat,
                        float* __restrict__ sq, float* __restrict__ sqb, int* __restrict__ deg)
{
    const int p = blockIdx.x * 256 + threadIdx.x;
    const int tile = p >> 4, j = p & 15;
    const float* src = x + (size_t)p * CIN;
    float e[CIN];
    #pragma unroll
    for (int i = 0; i < 8; ++i) {                  // i: 8-dim group; quad=i&3, h=i>>2
        float4 v0 = *reinterpret_cast<const float4*>(src + 8*i);
        float4 v1 = *reinterpret_cast<const float4*>(src + 8*i + 4);
        e[8*i+0]=v0.x; e[8*i+1]=v0.y; e[8*i+2]=v0.z; e[8*i+3]=v0.w;
        e[8*i+4]=v1.x; e[8*i+5]=v1.y; e[8*i+6]=v1.z; e[8*i+7]=v1.w;
        short8v h;
        #pragma unroll
        for (int u = 0; u < 8; ++u) h[u] = (short)f2bf(e[8*i+u]);
        *reinterpret_cast<short8v*>(xhi + (size_t)p*CIN + 8*i) = h;
        *reinterpret_cast<short8v*>(xat + (size_t)tile*1024 + (i>>2)*512 + ((i&3)*16 + j)*8) = h;
    }
    const float s = np_sq64(e);
    sq[p]  = s;           // exact (k2)
    sqb[p] = s + 16.f;    // biased (k1 keys; always > 0)
    deg[p] = 0;           // replaces memset
}

// Comparators: KA = ascending on key[], DD = descending on kd[].
#define KA(a,b) { const unsigned _x = key[a], _y = key[b]; key[a] = min(_x,_y); key[b] = max(_x,_y); }
#define DD(a,b) { const unsigned _x = kd[a],  _y = kd[b];  kd[a]  = max(_x,_y); kd[b]  = min(_x,_y); }
#define DDMERGE \
    DD(0,8)  DD(1,9)  DD(2,10) DD(3,11) DD(4,12) DD(5,13) DD(6,14) DD(7,15) \
    DD(0,4)  DD(1,5)  DD(2,6)  DD(3,7)  DD(8,12) DD(9,13) DD(10,14) DD(11,15) \
    DD(0,2)  DD(1,3)  DD(4,6)  DD(5,7)  DD(8,10) DD(9,11) DD(12,14) DD(13,15) \
    DD(0,1)  DD(2,3)  DD(4,5)  DD(6,7)  DD(8,9)  DD(10,11) DD(12,13) DD(14,15)

// ---------------- K1: MFMA swapped-operand KNN + Batcher-63 top-16 + cross-quad merge ----------------
__global__ __launch_bounds__(256,1) void k1_knn(const unsigned short* __restrict__ xhi,
                                                const unsigned short* __restrict__ xat,
                                                const float* __restrict__ sqb,
                                                unsigned* __restrict__ cand)
{
    const int wid  = ((blockIdx.x & 7) << 8) + (blockIdx.x >> 3);  // XCD swizzle (4 clouds/XCD)
    const int o    = wid >> 1;           // row group (64 rows)
    const int half = wid & 1;            // column half
    const int wave = threadIdx.x >> 6;
    const int lane = threadIdx.x & 63;
    const int j    = lane & 15;
    const int quad = lane >> 4;
    const int rowglob = o*64 + wave*16 + j;
    const int cloud   = rowglob >> 11;
    const int cbase   = cloud << 11;               // cloud base point id

    const short8v bhi0 = *reinterpret_cast<const short8v*>(xhi + (size_t)rowglob*CIN + quad*8);
    const short8v bhi1 = *reinterpret_cast<const short8v*>(xhi + (size_t)rowglob*CIN + quad*8 + 32);

    unsigned kd[16];                   // DESC: kd[0] = worst kept
    #pragma unroll
    for (int k = 0; k < 16; ++k) kd[k] = 0xFFFFFFFFu;

    const unsigned short* pt0 = xat + (size_t)(cloud*128 + half*64)*1024 + lane*8;
    const float*          ps0 = sqb + cbase + half*1024 + quad*4;

    short8v pfa0 = *reinterpret_cast<const short8v*>(pt0);
    short8v pfa1 = *reinterpret_cast<const short8v*>(pt0 + 512);

    for (int it4 = 0; it4 < 16; ++it4) {           // 16 batches x 4 tiles x 16 cols
        unsigned key[16];
        const unsigned idb = (unsigned)(half*1024 + it4*64 + quad*4) | 0x80000000u;

        {
            float4v acc0 = {0.f,0.f,0.f,0.f}, acc1 = {0.f,0.f,0.f,0.f};
            acc0 = __builtin_amdgcn_mfma_f32_16x16x32_bf16(pfa0, bhi0, acc0, 0,0,0);
            acc1 = __builtin_amdgcn_mfma_f32_16x16x32_bf16(pfa1, bhi1, acc1, 0,0,0);
            const float4v sqv = *reinterpret_cast<const float4v*>(ps0 + it4*64);
            #pragma unroll
            for (int r = 0; r < 4; ++r) {
                const float s = fmaf(-2.f, acc0[r] + acc1[r], sqv[r]);
                key[r] = (__float_as_uint(s) & 0xFFFFF800u) | (idb + (unsigned)r);
            }
        }
        {
            const int nxt = (it4 < 15) ? it4 + 1 : 15;
            const unsigned short* pan = pt0 + (size_t)(nxt*4)*1024;
            pfa0 = *reinterpret_cast<const short8v*>(pan);
            pfa1 = *reinterpret_cast<const short8v*>(pan + 512);
        }
        #pragma unroll
        for (int sub = 1; sub < 4; ++sub) {
            const unsigned short* pa = pt0 + (size_t)(it4*4 + sub)*1024;
            const short8v a0 = *reinterpret_cast<const short8v*>(pa);
            const short8v a1 = *reinterpret_cast<const short8v*>(pa + 512);
            float4v acc0 = {0.f,0.f,0.f,0.f}, acc1 = {0.f,0.f,0.f,0.f};
            acc0 = __builtin_amdgcn_mfma_f32_16x16x32_bf16(a0, bhi0, acc0, 0,0,0);
            acc1 = __builtin_amdgcn_mfma_f32_16x16x32_bf16(a1, bhi1, acc1, 0,0,0);
            const float4v sqv = *reinterpret_cast<const float4v*>(ps0 + it4*64 + sub*16);
            #pragma unroll
            for (int r = 0; r < 4; ++r) {
                const float s = fmaf(-2.f, acc0[r] + acc1[r], sqv[r]);
                key[sub*4 + r] = (__float_as_uint(s) & 0xFFFFF800u) | (idb + (unsigned)(sub*16 + r));
            }
        }

        // Batcher odd-even mergesort-16 ascending (63 comparators)
        KA(0,1) KA(2,3) KA(4,5) KA(6,7)
        KA(0,2) KA(1,3) KA(4,6) KA(5,7)
        KA(1,2) KA(5,6)
        KA(0,4) KA(1,5) KA(2,6) KA(3,7)
        KA(2,4) KA(3,5)
        KA(1,2) KA(3,4) KA(5,6)
        KA(8,9) KA(10,11) KA(12,13) KA(14,15)
        KA(8,10) KA(9,11) KA(12,14) KA(13,15)
        KA(9,10) KA(13,14)
        KA(8,12) KA(9,13) KA(10,14) KA(11,15)
        KA(10,12) KA(11,13)
        KA(9,10) KA(11,12) KA(13,14)
        KA(0,8) KA(1,9) KA(2,10) KA(3,11) KA(4,12) KA(5,13) KA(6,14) KA(7,15)
        KA(4,8) KA(5,9) KA(6,10) KA(7,11)
        KA(2,4) KA(3,5) KA(6,8) KA(7,9) KA(10,12) KA(11,13)
        KA(1,2) KA(3,4) KA(5,6) KA(7,8) KA(9,10) KA(11,12) KA(13,14)

        #pragma unroll
        for (int i = 0; i < 16; ++i) kd[i] = min(kd[i], key[i]);

        DDMERGE
    }

    // ---- cross-quad merge: 4 sorted-desc lists -> half's exact approx-top-16 ----
    #pragma unroll
    for (int lvl = 16; lvl <= 32; lvl <<= 1) {
        unsigned key[16];
        #pragma unroll
        for (int i = 0; i < 16; ++i) key[i] = __shfl_xor(kd[15-i], lvl);  // partner, reversed (asc)
        #pragma unroll
        for (int i = 0; i < 16; ++i) kd[i] = min(kd[i], key[i]);          // bottom-16 of union
        DDMERGE                                                            // restore desc
    }

    if (quad == 0) {                    // one lane per row writes the merged 16 keys
        unsigned* dst = cand + (size_t)rowglob*NCAND + half*16;
        #pragma unroll
        for (int k = 0; k < 4; ++k) {
            int4 w4 = { (int)kd[4*k+0], (int)kd[4*k+1], (int)kd[4*k+2], (int)kd[4*k+3] };
            *reinterpret_cast<int4*>(dst + 4*k) = w4;
        }
    }
}

// ---------------- K2: 2 points/wave; cross-lane bitonic sort-32 -> window -> exact rerank ----------------
__global__ void k2_refine(const float* __restrict__ x, const float* __restrict__ sq,
                          const unsigned* __restrict__ cand,
                          int* __restrict__ nbr, int* __restrict__ deg)
{
    const int hw   = threadIdx.x >> 5;                      // half-wave id 0..7
    const int w    = blockIdx.x * 8 + hw;                   // point id
    const int lane = threadIdx.x & 31;                      // lane within half
    const int gl   = threadIdx.x & 63;                      // lane within wave
    const unsigned long long hmask = (gl >= 32) ? 0xFFFFFFFF00000000ull : 0x00000000FFFFFFFFull;
    const int b    = w >> 11;
    const int ploc = w & (NPTS-1);
    const int cbase = b * NPTS;
    const float* xc = x + (size_t)cbase * CIN;
    const float* xp = xc + (size_t)ploc * CIN;

    // --- issue HBM loads up front (overlap with sort) ---
    unsigned kv = cand[(size_t)w * NCAND + lane];
    float xpl[CIN];
    #pragma unroll
    for (int i = 0; i < CIN/4; ++i) {
        float4 v = *reinterpret_cast<const float4*>(xp + 4*i);
        xpl[4*i+0]=v.x; xpl[4*i+1]=v.y; xpl[4*i+2]=v.z; xpl[4*i+3]=v.w;
    }
    const float sqp = sq[w];

    if ((int)(kv & 0x7FFu) == ploc) kv = 0xFFFFFFFFu;       // self-mask (sorts to top)

    // --- bitonic sort-32 across lanes (ascending by lane index within each half) ---
    #pragma unroll
    for (int k = 2; k <= 32; k <<= 1) {
        #pragma unroll
        for (int jj = k >> 1; jj >= 1; jj >>= 1) {
            const unsigned pv = __shfl_xor(kv, jj);         // jj<=16: stays within 32-half
            const bool takeMin = ((lane & k) == 0) == ((lane & jj) == 0);
            kv = takeMin ? min(kv, pv) : max(kv, pv);
        }
    }

    // --- window: 16th key's bit-11 floor == old radix T (bit-identical Tk) ---
    const unsigned k16key = __shfl(kv, 15, 32);
    const float d16 = fdec(k16key & 0xFFFFF800u);
    const unsigned Tk = (fenc(d16 + PREF_MARGIN) & 0xFFFFF800u) | 0x7FFu;  // inclusive

    const bool sv = (kv <= Tk);
    const int n = __popcll(__ballot(sv) & hmask);           // survivors = lanes 0..n-1 (prefix)
    const int qloc = (int)(kv & 0x7FFu);

    // --- fast path (per half): survivors == top-16 set ---
    if (n == KNN) {
        if (lane < KNN) {
            const int ng = cbase + qloc;
            nbr[(size_t)w * KNN + lane] = ng;
            atomicAdd(&deg[ng], 1);
        }
        return;
    }

    // --- exact np-faithful distance for survivors (1 chain/lane, lanes < n) ---
    float dot = 0.f;                               // sequential fp32, no FMA (verified recipe)
    if (lane < n) {
        const float* xq = xc + (size_t)qloc * CIN;
        #pragma unroll
        for (int i = 0; i < 8; ++i) {
            float4 v0 = *reinterpret_cast<const float4*>(xq + 8*i);
            float4 v1 = *reinterpret_cast<const float4*>(xq + 8*i + 4);
            float g[8] = {v0.x,v0.y,v0.z,v0.w,v1.x,v1.y,v1.z,v1.w};
            #pragma unroll
            for (int u = 0; u < 8; ++u)
                dot = __fadd_rn(dot, __fmul_rn(xpl[8*i+u], g[u]));
        }
    }
    const float sqq = sq[cbase + ((lane < n) ? qloc : 0)];
    float d = __fsub_rn(__fadd_rn(sqp, sqq), __fmul_rn(2.f, dot));
    int qcmp = qloc;
    if (lane >= n) { d = INFINITY; qcmp = 0x7fffffff; }

    // --- exact (d, idx) total-order rank, width-32 shuffles, 4-wide ---
    const int nn = (n + 3) & ~3;
    int rank = 0;
    for (int s = 0; s < nn; s += 4) {
        const float d0 = __shfl(d, s, 32),   d1 = __shfl(d, s+1, 32);
        const float d2 = __shfl(d, s+2, 32), d3 = __shfl(d, s+3, 32);
        const int   q0 = __shfl(qcmp, s, 32),   q1 = __shfl(qcmp, s+1, 32);
        const int   q2 = __shfl(qcmp, s+2, 32), q3 = __shfl(qcmp, s+3, 32);
        rank += (d0 < d || (d0 == d && q0 < qcmp)) ? 1 : 0;
        rank += (d1 < d || (d1 == d && q1 < qcmp)) ? 1 : 0;
        rank += (d2 < d || (d2 == d && q2 < qcmp)) ? 1 : 0;
        rank += (d3 < d || (d3 == d && q3 < qcmp)) ? 1 : 0;
    }
    if (lane < n && rank < KNN) {
        const int ng = cbase + qloc;
        nbr[(size_t)w * KNN + rank] = ng;
        atomicAdd(&deg[ng], 1);
    }
}

// ---------------- K3 scan, 3-phase coalesced (replaces single-block strided scan) ----------------
// Old k3_scan: thread t read deg[t*256+i] (lanes 1KB apart -> 64 txns/wave-load,
// ~128K txns on ONE CU + serial thread-0 scan) — an invisible ~40-70us single-block
// serial tail just under the profiler's top-5 cutoff. Split: A) 256 blocks, coalesced
// load + 8-step LDS scan; B) 1 tiny block scans 256 chunk sums (+ zeroes sums);
// C) 256 blocks add chunk bases, mirror cursor into deg.
__global__ void k3_scanA(const int* __restrict__ deg, int* __restrict__ rowstart,
                         int* __restrict__ chunksum)
{
    __shared__ int buf[256];
    const int t = threadIdx.x;
    const int g = blockIdx.x * 256 + t;
    const int v = deg[g];
    buf[t] = v;
    __syncthreads();
    int val = v;
    #pragma unroll
    for (int off = 1; off < 256; off <<= 1) {
        const int add = (t >= off) ? buf[t - off] : 0;
        __syncthreads();
        val += add;
        buf[t] = val;
        __syncthreads();
    }
    rowstart[g] = val - v;                       // chunk-local exclusive
    if (t == 255) chunksum[blockIdx.x] = val;    // chunk total
}

__global__ void k3_scanB(int* __restrict__ chunksum, int* __restrict__ rowstart,
                         double* __restrict__ sums)
{
    __shared__ int buf[256];
    const int t = threadIdx.x;
    sums[t] = 0.0;                               // zero BN accumulators (2*COUT = 256)
    const int v = chunksum[t];
    buf[t] = v;
    __syncthreads();
    int val = v;
    #pragma unroll
    for (int off = 1; off < 256; off <<= 1) {
        const int add = (t >= off) ? buf[t - off] : 0;
        __syncthreads();
        val += add;
        buf[t] = val;
        __syncthreads();
    }
    chunksum[t] = val - v;                       // exclusive chunk base (in place)
    if (t == 255) rowstart[NTOT] = val;          // total edge count
}

__global__ void k3_scanC(const int* __restrict__ chunkbase, int* __restrict__ rowstart,
                         int* __restrict__ deg)
{
    const int g = blockIdx.x * 256 + threadIdx.x;
    const int v = rowstart[g] + chunkbase[blockIdx.x];
    rowstart[g] = v;
    deg[g] = v;                                  // write cursor for k3_place
}

// ---------------- K3a: place edges into reverse lists (counter atomics only) ----------------
__global__ void k3_place(const int* __restrict__ nbr, int* __restrict__ wcur, int* __restrict__ rev)
{
    const int e = blockIdx.x * 256 + threadIdx.x;
    const int c = e >> 4;
    const int n = nbr[e];
    const int pos = atomicAdd(&wcur[n], 1);
    rev[pos] = c;
}

// ---------------- K3g: gather-max, direct broadcast index loads, 8 rows in flight ----------------
__global__ void k3_gather(const float* __restrict__ x, const int* __restrict__ rowstart,
                          const int* __restrict__ rev, float* __restrict__ pooled)
{
    const int n    = blockIdx.x * 4 + (threadIdx.x >> 6);
    const int lane = threadIdx.x & 63;
    const int s = rowstart[n];
    const int e = rowstart[n+1];
    float a0 = -INFINITY, a1 = -INFINITY, a2 = -INFINITY, a3 = -INFINITY;
    int i = s;
    for (; i + 8 <= e; i += 8) {
        const int c0 = rev[i+0], c1 = rev[i+1], c2 = rev[i+2], c3 = rev[i+3];
        const int c4 = rev[i+4], c5 = rev[i+5], c6 = rev[i+6], c7 = rev[i+7];
        const float v0 = x[(size_t)c0 * CIN + lane];
        const float v1 = x[(size_t)c1 * CIN + lane];
        const float v2 = x[(size_t)c2 * CIN + lane];
        const float v3 = x[(size_t)c3 * CIN + lane];
        const float v4 = x[(size_t)c4 * CIN + lane];
        const float v5 = x[(size_t)c5 * CIN + lane];
        const float v6 = x[(size_t)c6 * CIN + lane];
        const float v7 = x[(size_t)c7 * CIN + lane];
        a0 = fmaxf(a0, v0); a1 = fmaxf(a1, v1); a2 = fmaxf(a2, v2); a3 = fmaxf(a3, v3);
        a0 = fmaxf(a0, v4); a1 = fmaxf(a1, v5); a2 = fmaxf(a2, v6); a3 = fmaxf(a3, v7);
    }
    for (; i < e; ++i)
        a0 = fmaxf(a0, x[(size_t)rev[i] * CIN + lane]);
    float acc = fmaxf(fmaxf(a0, a1), fmaxf(a2, a3));
    if (e == s) acc = 0.f;                                  // empty row -> 0 (torch_scatter)
    pooled[(size_t)n * CIN + lane] = acc;
}

// ---------------- K4: y = pooled @ W^T + b, with fused per-channel stats ----------------
__global__ __launch_bounds__(256,2) void k4_linear(const float* __restrict__ pooled, const float* __restrict__ W,
                                                   const float* __restrict__ bias, float* __restrict__ y,
                                                   double* __restrict__ sums)
{
    __shared__ float wl[COUT*68];
    __shared__ float pl[64*68];     // reused post-loop as 2x[16][128] stat partials
    const int t  = threadIdx.x;
    const int r0 = blockIdx.x * 64;
    for (int i = 0; i < (COUT*CIN)/256; ++i) {
        int linear = t + 256*i;
        int c = linear >> 6, k = linear & 63;
        wl[c*68 + k] = W[linear];
    }
    for (int i = 0; i < (64*CIN)/256; ++i) {
        int linear = t + 256*i;
        int r = linear >> 6, k = linear & 63;
        pl[r*68 + k] = pooled[(size_t)(r0 + r)*CIN + k];
    }
    __syncthreads();
    const int tx = t & 15;
    const int ty = t >> 4;
    float acc[4][8];
    #pragma unroll
    for (int j = 0; j < 8; ++j) {
        float bj = bias[tx + 16*j];
        #pragma unroll
        for (int i = 0; i < 4; ++i) acc[i][j] = bj;
    }
    for (int k = 0; k < CIN; k += 4) {
        float4 a[4], bb[8];
        #pragma unroll
        for (int i = 0; i < 4; ++i) a[i]  = *reinterpret_cast<const float4*>(&pl[(ty*4+i)*68 + k]);
        #pragma unroll
        for (int j = 0; j < 8; ++j) bb[j] = *reinterpret_cast<const float4*>(&wl[(tx+16*j)*68 + k]);
        #pragma unroll
        for (int i = 0; i < 4; ++i)
            #pragma unroll
            for (int j = 0; j < 8; ++j) {
                acc[i][j] = fmaf(a[i].x, bb[j].x, acc[i][j]);
                acc[i][j] = fmaf(a[i].y, bb[j].y, acc[i][j]);
                acc[i][j] = fmaf(a[i].z, bb[j].z, acc[i][j]);
                acc[i][j] = fmaf(a[i].w, bb[j].w, acc[i][j]);
            }
    }
    #pragma unroll
    for (int i = 0; i < 4; ++i) {
        float* dst = y + (size_t)(r0 + ty*4 + i) * COUT;
        #pragma unroll
        for (int j = 0; j < 8; ++j) dst[tx + 16*j] = acc[i][j];
    }
    // --- fused stats ---
    __syncthreads();
    #pragma unroll
    for (int j = 0; j < 8; ++j) {
        float s  = ((acc[0][j] + acc[1][j]) + (acc[2][j] + acc[3][j]));
        float ss = ((acc[0][j]*acc[0][j] + acc[1][j]*acc[1][j]) +
                    (acc[2][j]*acc[2][j] + acc[3][j]*acc[3][j]));
        pl[ty*COUT + tx + 16*j]        = s;
        pl[2048 + ty*COUT + tx + 16*j] = ss;
    }
    __syncthreads();
    if (t < COUT) {
        double S = 0.0, SS = 0.0;
        #pragma unroll
        for (int r = 0; r < 16; ++r) {
            S  += (double)pl[r*COUT + t];
            SS += (double)pl[2048 + r*COUT + t];
        }
        atomicAdd(&sums[t], S);
        atomicAdd(&sums[COUT + t], SS);
    }
}

// ---------------- K6: BN scale/shift ----------------
__global__ void k6_bnparam(const double* __restrict__ sums, const float* __restrict__ gamma,
                           const float* __restrict__ beta, float* __restrict__ scsh)
{
    const int t = threadIdx.x;
    const double mean = sums[t] * (1.0/NTOT);
    const double var  = sums[COUT + t] * (1.0/NTOT) - mean*mean;
    const float inv   = (float)rsqrt(var + 1e-5);
    const float sc    = inv * gamma[t];
    scsh[t]        = sc;
    scsh[COUT + t] = beta[t] - (float)mean * sc;
}

// ---------------- K7: out = relu(y*scale + shift) ----------------
__global__ void k7_bnrelu(const float* __restrict__ y, const float* __restrict__ scsh, float* __restrict__ out)
{
    const int g    = blockIdx.x * blockDim.x + threadIdx.x;
    const int base = g * 4;
    float4 v = *reinterpret_cast<const float4*>(y + base);
    const int ch = base & (COUT-1);
    float4 o;
    o.x = fmaxf(0.f, fmaf(v.x, scsh[ch+0], scsh[COUT+ch+0]));
    o.y = fmaxf(0.f, fmaf(v.y, scsh[ch+1], scsh[COUT+ch+1]));
    o.z = fmaxf(0.f, fmaf(v.z, scsh[ch+2], scsh[COUT+ch+2]));
    o.w = fmaxf(0.f, fmaf(v.w, scsh[ch+3], scsh[COUT+ch+3]));
    *reinterpret_cast<float4*>(out + base) = o;
}

extern "C" void kernel_launch(void* const* d_in, const int* in_sizes, int n_in,
                              void* d_out, int out_size, void* d_ws, size_t ws_size,
                              hipStream_t stream)
{
    const float* x     = (const float*)d_in[0];
    const float* W     = (const float*)d_in[2];
    const float* bias  = (const float*)d_in[3];
    const float* gamma = (const float*)d_in[4];
    const float* beta  = (const float*)d_in[5];
    float* out = (float*)d_out;

    // Workspace — explicit 16B-aligned byte offsets (layout as rounds 20/21 + chunksum):
    char* ws = (char*)d_ws;
    unsigned short* xhi = (unsigned short*)ws;
    unsigned short* xat = (unsigned short*)(ws + (size_t)NTOT*128);
    float*    pooled   = (float*)ws;
    unsigned* cand     = (unsigned*)(ws + (size_t)NTOT*256);
    float*    y        = (float*)(ws + (size_t)NTOT*256);
    int*      nbr      = (int*)(ws + (size_t)NTOT*768);
    int*      deg      = (int*)(ws + (size_t)NTOT*832);            // becomes wcur after scanC
    int*      rowstart = (int*)(ws + (size_t)NTOT*836);
    int*      rev      = (int*)(ws + (size_t)NTOT*840 + 16);
    float*    sqb      = (float*)rev;                              // aliased: k0->k1 only
    float*    sq       = (float*)(ws + (size_t)NTOT*904 + 16);
    double*   sums     = (double*)(ws + (size_t)NTOT*908 + 16);    // 16B aligned
    float*    scsh     = (float*)(ws + (size_t)NTOT*908 + 16 + 2048);
    int*      chunksum = (int*)(ws + (size_t)NTOT*908 + 16 + 2048 + 1024);  // 256 ints

    k0_prep  <<<NTOT/256,   256, 0, stream>>>(x, xhi, xat, sq, sqb, deg);
    k1_knn   <<<NTOT/32,    256, 0, stream>>>(xhi, xat, sqb, cand);   // 2048 blocks
    k2_refine<<<NTOT/8,     256, 0, stream>>>(x, sq, cand, nbr, deg); // 2 points/wave, no LDS

    k3_scanA <<<NTOT/256,   256, 0, stream>>>(deg, rowstart, chunksum);
    k3_scanB <<<1,          256, 0, stream>>>(chunksum, rowstart, sums);
    k3_scanC <<<NTOT/256,   256, 0, stream>>>(chunksum, rowstart, deg);
    k3_place <<<NTOT*KNN/256,256,0, stream>>>(nbr, deg, rev);
    k3_gather<<<NTOT/4,     256, 0, stream>>>(x, rowstart, rev, pooled);

    k4_linear <<<NTOT/64, 256, 0, stream>>>(pooled, W, bias, y, sums);
    k6_bnparam<<<1,      COUT, 0, stream>>>(sums, gamma, beta, scsh);
    k7_bnrelu <<<(NTOT*COUT/4)/256, 256, 0, stream>>>(y, scsh, out);
}